// Round 1
// baseline (197.277 us; speedup 1.0000x reference)
//
#include <hip/hip_runtime.h>
#include <math.h>

#define Bg 256
#define Nn 4096
#define Ee 65536
#define Kk (Nn * 3)   // 12288
#define NPB 4         // nodes per block in k_main

// ---------------- degree histogram ----------------
__global__ __launch_bounds__(256) void k_degrees(const int* __restrict__ src,
                                                 const int* __restrict__ dst,
                                                 int* __restrict__ deg_out,
                                                 int* __restrict__ deg_in) {
    int e = blockIdx.x * 256 + threadIdx.x;
    if (e < Ee) {
        atomicAdd(&deg_out[src[e]], 1);
        atomicAdd(&deg_in[dst[e]], 1);
    }
}

// ---------------- norms + exclusive scan of deg_in (single block) ----------------
__global__ __launch_bounds__(256) void k_norm_scan(const int* __restrict__ deg_out,
                                                   const int* __restrict__ deg_in,
                                                   float* __restrict__ c_src,
                                                   float* __restrict__ c_dst,
                                                   int* __restrict__ row_ptr) {
    __shared__ int part[256];
    int t = threadIdx.x;
    int base = t * 16;
    int local[16];
    int s = 0;
#pragma unroll
    for (int i = 0; i < 16; i++) {
        int di = deg_in[base + i];
        local[i] = di;
        s += di;
        c_dst[base + i] = rsqrtf(fmaxf((float)di, 1.0f));
        int dq = deg_out[base + i];
        c_src[base + i] = rsqrtf(fmaxf((float)dq, 1.0f));
    }
    part[t] = s;
    __syncthreads();
    if (t == 0) {
        int run = 0;
        for (int i = 0; i < 256; i++) { int v = part[i]; part[i] = run; run += v; }
    }
    __syncthreads();
    int run = part[t];
#pragma unroll
    for (int i = 0; i < 16; i++) { row_ptr[base + i] = run; run += local[i]; }
    if (t == 255) row_ptr[Nn] = run;   // == Ee
}

// ---------------- CSR fill (sorted-by-dst source list) ----------------
__global__ __launch_bounds__(256) void k_fill(const int* __restrict__ src,
                                              const int* __restrict__ dst,
                                              const int* __restrict__ row_ptr,
                                              int* __restrict__ cursor,
                                              int* __restrict__ csr_src) {
    int e = blockIdx.x * 256 + threadIdx.x;
    if (e < Ee) {
        int d = dst[e];
        int ofs = atomicAdd(&cursor[d], 1);
        csr_src[row_ptr[d] + ofs] = src[e];
    }
}

// ---------------- scaled transpose: xs[k][b] = x[b][k] * c_src[k/3],  k = n*3+c ----------------
__global__ __launch_bounds__(256) void k_transpose(const float* __restrict__ x,
                                                   const float* __restrict__ c_src,
                                                   float* __restrict__ xs) {
    __shared__ float tile[64][65];
    int k0 = blockIdx.x * 64;   // over Kk = 12288 -> 192 blocks
    int b0 = blockIdx.y * 64;   // over Bg = 256   -> 4 blocks
    int t = threadIdx.x;
    int kk = t & 63, bi = t >> 6;
#pragma unroll
    for (int i = 0; i < 16; i++) {
        int bb = bi + i * 4;
        tile[bb][kk] = x[(size_t)(b0 + bb) * Kk + k0 + kk];
    }
    __syncthreads();
    int bb2 = t & 63, ki = t >> 6;
#pragma unroll
    for (int i = 0; i < 16; i++) {
        int kk2 = ki + i * 4;
        xs[(size_t)(k0 + kk2) * Bg + b0 + bb2] = tile[bb2][kk2] * c_src[(k0 + kk2) / 3];
    }
}

// ---------------- fused gather + (3->64) matmul + relu + Wfc dot ----------------
__global__ __launch_bounds__(256) void k_main(const float* __restrict__ xs,
                                              const float* __restrict__ W1,
                                              const float* __restrict__ b1,
                                              const float* __restrict__ Wfc,
                                              const float* __restrict__ c_dst,
                                              const int* __restrict__ row_ptr,
                                              const int* __restrict__ csr_src,
                                              float* __restrict__ out_acc) {
    __shared__ float sW1[192];
    __shared__ float sb1[64];
    __shared__ float sWfc[NPB * 64];
    int t = threadIdx.x;      // t = batch index b
    int n0 = blockIdx.x * NPB;
    if (t < 192) sW1[t] = W1[t];
    else sb1[t - 192] = b1[t - 192];
    sWfc[t] = Wfc[n0 * 64 + t];   // NPB*64 == 256 floats
    __syncthreads();

    float total = 0.f;
    for (int j = 0; j < NPB; j++) {
        int n = n0 + j;
        int s0 = row_ptr[n], s1 = row_ptr[n + 1];
        float a0 = 0.f, a1 = 0.f, a2 = 0.f;
        for (int i = s0; i < s1; i++) {
            int sv = csr_src[i];                      // wave-uniform
            const float* p = xs + (size_t)sv * (3 * Bg);
            a0 += p[t];
            a1 += p[Bg + t];
            a2 += p[2 * Bg + t];
        }
        float cd = c_dst[n];
        a0 *= cd; a1 *= cd; a2 *= cd;
        float part = 0.f;
#pragma unroll
        for (int f = 0; f < 64; f++) {
            float h = fmaf(a0, sW1[f], fmaf(a1, sW1[64 + f], fmaf(a2, sW1[128 + f], sb1[f])));
            h = fmaxf(h, 0.f);
            part = fmaf(h, sWfc[j * 64 + f], part);
        }
        total += part;
    }
    atomicAdd(&out_acc[t], total);
}

// ---------------- epilogue: sigmoid ----------------
__global__ __launch_bounds__(256) void k_final(const float* __restrict__ out_acc,
                                               const float* __restrict__ bfc,
                                               float* __restrict__ out) {
    int t = threadIdx.x;
    float v = out_acc[t] + bfc[0];
    out[t] = 1.0f / (1.0f + expf(-v));
}

extern "C" void kernel_launch(void* const* d_in, const int* in_sizes, int n_in,
                              void* d_out, int out_size, void* d_ws, size_t ws_size,
                              hipStream_t stream) {
    const float* x   = (const float*)d_in[0];
    const float* W1  = (const float*)d_in[1];
    const float* b1  = (const float*)d_in[2];
    const float* Wfc = (const float*)d_in[3];
    const float* bfc = (const float*)d_in[4];
    const int*   src = (const int*)d_in[5];
    const int*   dst = (const int*)d_in[6];
    float* out = (float*)d_out;

    char* ws = (char*)d_ws;
    // xs: Kk*Bg floats = 12,582,912 bytes
    float* xs = (float*)ws;
    const size_t Z = (size_t)Kk * Bg * 4;
    // zeroed-together block: deg_out | deg_in | cursor | out_acc  (50176 B)
    int*   deg_out = (int*)(ws + Z);
    int*   deg_in  = (int*)(ws + Z + 16384);
    int*   cursor  = (int*)(ws + Z + 32768);
    float* out_acc = (float*)(ws + Z + 49152);
    float* c_src   = (float*)(ws + Z + 50176);
    float* c_dst   = (float*)(ws + Z + 66560);
    int*   row_ptr = (int*)(ws + Z + 82944);   // 4097 ints
    int*   csr_src = (int*)(ws + Z + 99344);   // 65536 ints -> end ~12.94 MB

    hipMemsetAsync(ws + Z, 0, 50176, stream);
    k_degrees<<<Ee / 256, 256, 0, stream>>>(src, dst, deg_out, deg_in);
    k_norm_scan<<<1, 256, 0, stream>>>(deg_out, deg_in, c_src, c_dst, row_ptr);
    k_fill<<<Ee / 256, 256, 0, stream>>>(src, dst, row_ptr, cursor, csr_src);
    k_transpose<<<dim3(Kk / 64, Bg / 64), 256, 0, stream>>>(x, c_src, xs);
    k_main<<<Nn / NPB, 256, 0, stream>>>(xs, W1, b1, Wfc, c_dst, row_ptr, csr_src, out_acc);
    k_final<<<1, 256, 0, stream>>>(out_acc, bfc, out);
}

// Round 2
// 130.143 us; speedup vs baseline: 1.5158x; 1.5158x over previous
//
#include <hip/hip_runtime.h>
#include <math.h>

#define Bg 256
#define Nn 4096
#define Ee 65536
#define Kk (Nn * 3)   // 12288

// ---------------- degree histogram ----------------
__global__ __launch_bounds__(256) void k_degrees(const int* __restrict__ src,
                                                 const int* __restrict__ dst,
                                                 int* __restrict__ deg_out,
                                                 int* __restrict__ deg_in) {
    int e = blockIdx.x * 256 + threadIdx.x;
    if (e < Ee) {
        atomicAdd(&deg_out[src[e]], 1);
        atomicAdd(&deg_in[dst[e]], 1);
    }
}

// ---------------- norms + exclusive scan of deg_in (parallel) ----------------
__global__ __launch_bounds__(256) void k_norm_scan(const int* __restrict__ deg_out,
                                                   const int* __restrict__ deg_in,
                                                   float* __restrict__ c_src,
                                                   float* __restrict__ c_dst,
                                                   int* __restrict__ row_ptr) {
    int t = threadIdx.x;
    int base = t * 16;
    int local[16];
    int s = 0;
#pragma unroll
    for (int i = 0; i < 16; i++) {
        int di = deg_in[base + i];
        local[i] = di;
        s += di;
        c_dst[base + i] = rsqrtf(fmaxf((float)di, 1.0f));
        int dq = deg_out[base + i];
        c_src[base + i] = rsqrtf(fmaxf((float)dq, 1.0f));
    }
    // inclusive wave scan of s
    int lane = t & 63, w = t >> 6;
    int inc = s;
#pragma unroll
    for (int d = 1; d < 64; d <<= 1) {
        int v = __shfl_up(inc, d, 64);
        if (lane >= d) inc += v;
    }
    __shared__ int wtot[4], woff[4];
    if (lane == 63) wtot[w] = inc;
    __syncthreads();
    if (t == 0) { int run = 0; for (int i = 0; i < 4; i++) { woff[i] = run; run += wtot[i]; } }
    __syncthreads();
    int run = inc - s + woff[w];   // exclusive prefix for this thread
#pragma unroll
    for (int i = 0; i < 16; i++) { row_ptr[base + i] = run; run += local[i]; }
    if (t == 255) row_ptr[Nn] = run;   // == Ee
}

// ---------------- CSR fill (sorted-by-dst source list) ----------------
__global__ __launch_bounds__(256) void k_fill(const int* __restrict__ src,
                                              const int* __restrict__ dst,
                                              const int* __restrict__ row_ptr,
                                              int* __restrict__ cursor,
                                              int* __restrict__ csr_src) {
    int e = blockIdx.x * 256 + threadIdx.x;
    if (e < Ee) {
        int d = dst[e];
        int ofs = atomicAdd(&cursor[d], 1);
        csr_src[row_ptr[d] + ofs] = src[e];
    }
}

// ---------------- scaled transpose into XCD slabs ----------------
// xs2[bq][n][bl][c] = x[bq*64+bl][n][c] * c_src[n];  slab = 4096*192 floats (3.15 MB)
__global__ __launch_bounds__(256) void k_transpose(const float* __restrict__ x,
                                                   const float* __restrict__ c_src,
                                                   float* __restrict__ xs2) {
    __shared__ float tile[64][193];
    int t = threadIdx.x;
    int n0 = blockIdx.x * 64;       // 64 blocks over nodes
    int bq = blockIdx.y;            // 4 slabs
    const float* xb = x + (size_t)bq * 64 * Kk + (size_t)n0 * 3;
#pragma unroll 8
    for (int i = 0; i < 48; i++) {
        int flat = i * 256 + t;
        int bi = flat / 192, kk = flat - bi * 192;
        tile[bi][kk] = xb[(size_t)bi * Kk + kk];
    }
    __syncthreads();
    float* outp = xs2 + (size_t)bq * (Nn * 192) + (size_t)n0 * 192;
#pragma unroll 8
    for (int i = 0; i < 48; i++) {
        int o = i * 256 + t;
        int nn = o / 192; int r = o - nn * 192;
        int bl = r / 3;   int c = r - bl * 3;
        outp[o] = tile[bl][nn * 3 + c] * c_src[n0 + nn];
    }
}

// ---------------- fused gather + (3->64) matmul + relu + Wfc dot ----------------
template <int NPB>
__global__ __launch_bounds__(64) void k_main(const float* __restrict__ xs2,
                                             const float* __restrict__ W1,
                                             const float* __restrict__ b1,
                                             const float* __restrict__ Wfc,
                                             const float* __restrict__ c_dst,
                                             const int* __restrict__ row_ptr,
                                             const int* __restrict__ csr_src,
                                             float* __restrict__ partial) {
    __shared__ float4 sW14[64];
    __shared__ float sWfc[NPB * 64];
    int t = threadIdx.x;               // lane = low 6 bits of batch
    int bq = blockIdx.x & 3;           // slab; blockIdx%8 -> XCD, so XCD k serves slab k%4
    int g  = blockIdx.x >> 2;          // node group
    int n0 = g * NPB;
    sW14[t] = make_float4(W1[t], W1[64 + t], W1[128 + t], b1[t]);
#pragma unroll
    for (int j = 0; j < NPB; j++) sWfc[j * 64 + t] = Wfc[(n0 + j) * 64 + t];
    __syncthreads();

    const float* slab = xs2 + (size_t)bq * (Nn * 192);
    float acc[NPB][3];
#pragma unroll
    for (int j = 0; j < NPB; j++) {
        int s0 = row_ptr[n0 + j], s1 = row_ptr[n0 + j + 1];
        float a0 = 0.f, a1 = 0.f, a2 = 0.f;
        int i = s0;
        for (; i + 4 <= s1; i += 4) {
            const float* p0 = slab + csr_src[i]     * 192 + t * 3;
            const float* p1 = slab + csr_src[i + 1] * 192 + t * 3;
            const float* p2 = slab + csr_src[i + 2] * 192 + t * 3;
            const float* p3 = slab + csr_src[i + 3] * 192 + t * 3;
            float u0 = p0[0], u1 = p0[1], u2 = p0[2];
            float v0 = p1[0], v1 = p1[1], v2 = p1[2];
            float w0 = p2[0], w1 = p2[1], w2 = p2[2];
            float z0 = p3[0], z1 = p3[1], z2 = p3[2];
            a0 += (u0 + v0) + (w0 + z0);
            a1 += (u1 + v1) + (w1 + z1);
            a2 += (u2 + v2) + (w2 + z2);
        }
        for (; i < s1; i++) {
            const float* p = slab + csr_src[i] * 192 + t * 3;
            a0 += p[0]; a1 += p[1]; a2 += p[2];
        }
        float cd = c_dst[n0 + j];
        acc[j][0] = a0 * cd; acc[j][1] = a1 * cd; acc[j][2] = a2 * cd;
    }

    float part[NPB];
#pragma unroll
    for (int j = 0; j < NPB; j++) part[j] = 0.f;
#pragma unroll 16
    for (int f = 0; f < 64; f++) {
        float4 w = sW14[f];
#pragma unroll
        for (int j = 0; j < NPB; j++) {
            float h = fmaf(acc[j][0], w.x, fmaf(acc[j][1], w.y, fmaf(acc[j][2], w.z, w.w)));
            h = fmaxf(h, 0.f);
            part[j] = fmaf(h, sWfc[j * 64 + f], part[j]);
        }
    }
    float tot = 0.f;
#pragma unroll
    for (int j = 0; j < NPB; j++) tot += part[j];
    partial[(size_t)g * 256 + bq * 64 + t] = tot;   // coalesced 256B per block
}

// ---------------- reduce partials over node groups ----------------
__global__ __launch_bounds__(256) void k_reduce(const float* __restrict__ partial,
                                                float* __restrict__ out_acc,
                                                int chunk) {
    int t = threadIdx.x;
    int g0 = blockIdx.x * chunk;
    float s = 0.f;
    for (int g = 0; g < chunk; g++) s += partial[(size_t)(g0 + g) * 256 + t];
    atomicAdd(&out_acc[t], s);
}

// ---------------- epilogue: sigmoid ----------------
__global__ __launch_bounds__(256) void k_final(const float* __restrict__ out_acc,
                                               const float* __restrict__ bfc,
                                               float* __restrict__ out) {
    int t = threadIdx.x;
    float v = out_acc[t] + bfc[0];
    out[t] = 1.0f / (1.0f + expf(-v));
}

extern "C" void kernel_launch(void* const* d_in, const int* in_sizes, int n_in,
                              void* d_out, int out_size, void* d_ws, size_t ws_size,
                              hipStream_t stream) {
    const float* x   = (const float*)d_in[0];
    const float* W1  = (const float*)d_in[1];
    const float* b1  = (const float*)d_in[2];
    const float* Wfc = (const float*)d_in[3];
    const float* bfc = (const float*)d_in[4];
    const int*   src = (const int*)d_in[5];
    const int*   dst = (const int*)d_in[6];
    float* out = (float*)d_out;

    char* ws = (char*)d_ws;
    float* xs2 = (float*)ws;                       // 4 slabs x 3,145,728 B = 12,582,912 B
    const size_t Z = (size_t)Kk * Bg * 4;
    int*   deg_out = (int*)(ws + Z);               // zeroed block: 50176 B total
    int*   deg_in  = (int*)(ws + Z + 16384);
    int*   cursor  = (int*)(ws + Z + 32768);
    float* out_acc = (float*)(ws + Z + 49152);
    float* c_src   = (float*)(ws + Z + 50176);
    float* c_dst   = (float*)(ws + Z + 66560);
    int*   row_ptr = (int*)(ws + Z + 82944);       // 4097 ints
    int*   csr_src = (int*)(ws + Z + 99344);       // 65536 ints
    size_t poff    = Z + 99344 + 262144;           // partial buffer start (~12.94 MB)
    float* partial = (float*)(ws + poff);

    hipMemsetAsync(ws + Z, 0, 50176, stream);
    k_degrees<<<Ee / 256, 256, 0, stream>>>(src, dst, deg_out, deg_in);
    k_norm_scan<<<1, 256, 0, stream>>>(deg_out, deg_in, c_src, c_dst, row_ptr);
    k_fill<<<Ee / 256, 256, 0, stream>>>(src, dst, row_ptr, cursor, csr_src);
    k_transpose<<<dim3(Nn / 64, 4), 256, 0, stream>>>(x, c_src, xs2);

    // pick NPB by available workspace for the partial buffer
    if (ws_size >= poff + (size_t)(Nn / 2) * 256 * 4) {
        const int NPB = 2;                         // 8192 blocks, partial = 2 MB
        k_main<NPB><<<(Nn / NPB) * 4, 64, 0, stream>>>(xs2, W1, b1, Wfc, c_dst, row_ptr, csr_src, partial);
        k_reduce<<<256, 256, 0, stream>>>(partial, out_acc, (Nn / NPB) / 256);
    } else {
        const int NPB = 8;                         // 2048 blocks, partial = 0.5 MB
        k_main<NPB><<<(Nn / NPB) * 4, 64, 0, stream>>>(xs2, W1, b1, Wfc, c_dst, row_ptr, csr_src, partial);
        k_reduce<<<256, 256, 0, stream>>>(partial, out_acc, (Nn / NPB) / 256);
    }
    k_final<<<1, 256, 0, stream>>>(out_acc, bfc, out);
}

// Round 3
// 125.958 us; speedup vs baseline: 1.5662x; 1.0332x over previous
//
#include <hip/hip_runtime.h>
#include <math.h>

#define Bg 256
#define Nn 4096
#define Ee 65536
#define Kk (Nn * 3)   // 12288

// ---------------- degree histogram ----------------
__global__ __launch_bounds__(256) void k_degrees(const int* __restrict__ src,
                                                 const int* __restrict__ dst,
                                                 int* __restrict__ deg_out,
                                                 int* __restrict__ deg_in) {
    int e = blockIdx.x * 256 + threadIdx.x;
    if (e < Ee) {
        atomicAdd(&deg_out[src[e]], 1);
        atomicAdd(&deg_in[dst[e]], 1);
    }
}

// ---------------- norms + exclusive scan of deg_in (parallel) ----------------
__global__ __launch_bounds__(256) void k_norm_scan(const int* __restrict__ deg_out,
                                                   const int* __restrict__ deg_in,
                                                   float* __restrict__ c_src,
                                                   float* __restrict__ c_dst,
                                                   int* __restrict__ row_ptr) {
    int t = threadIdx.x;
    int base = t * 16;
    int local[16];
    int s = 0;
#pragma unroll
    for (int i = 0; i < 16; i++) {
        int di = deg_in[base + i];
        local[i] = di;
        s += di;
        c_dst[base + i] = rsqrtf(fmaxf((float)di, 1.0f));
        int dq = deg_out[base + i];
        c_src[base + i] = rsqrtf(fmaxf((float)dq, 1.0f));
    }
    int lane = t & 63, w = t >> 6;
    int inc = s;
#pragma unroll
    for (int d = 1; d < 64; d <<= 1) {
        int v = __shfl_up(inc, d, 64);
        if (lane >= d) inc += v;
    }
    __shared__ int wtot[4], woff[4];
    if (lane == 63) wtot[w] = inc;
    __syncthreads();
    if (t == 0) { int run = 0; for (int i = 0; i < 4; i++) { woff[i] = run; run += wtot[i]; } }
    __syncthreads();
    int run = inc - s + woff[w];
#pragma unroll
    for (int i = 0; i < 16; i++) { row_ptr[base + i] = run; run += local[i]; }
    if (t == 255) row_ptr[Nn] = run;
}

// ---------------- CSR fill ----------------
__global__ __launch_bounds__(256) void k_fill(const int* __restrict__ src,
                                              const int* __restrict__ dst,
                                              const int* __restrict__ row_ptr,
                                              int* __restrict__ cursor,
                                              int* __restrict__ csr_src) {
    int e = blockIdx.x * 256 + threadIdx.x;
    if (e < Ee) {
        int d = dst[e];
        int ofs = atomicAdd(&cursor[d], 1);
        csr_src[row_ptr[d] + ofs] = src[e];
    }
}

// ---------------- scaled transpose into XCD slabs (float4 IO) ----------------
// xs2[bq][n][bl*3+c] = x[bq*64+bl][n][c] * c_src[n];  slab = 4096*192 floats (3.15 MB)
__global__ __launch_bounds__(256) void k_transpose(const float* __restrict__ x,
                                                   const float* __restrict__ c_src,
                                                   float* __restrict__ xs2) {
    __shared__ float4 tile4[64][49];           // row stride 196 floats (784 B, 16-aligned)
    int t = threadIdx.x;
    int n0 = blockIdx.x * 64;
    int bq = blockIdx.y;
    const float* xb = x + (size_t)bq * 64 * Kk + (size_t)n0 * 3;
#pragma unroll
    for (int i = 0; i < 12; i++) {
        int idx = i * 256 + t;
        int bi = idx / 48, j = idx - bi * 48;
        tile4[bi][j] = ((const float4*)(xb + (size_t)bi * Kk))[j];
    }
    __syncthreads();
    const float* tile = (const float*)tile4;   // [64][196]
    float4* outp = (float4*)(xs2 + (size_t)bq * (Nn * 192) + (size_t)n0 * 192);
#pragma unroll
    for (int i = 0; i < 12; i++) {
        int o4 = i * 256 + t;
        int nn = o4 / 48, q = o4 - nn * 48;
        int f0 = q * 4;
        float cs = c_src[n0 + nn];
        float4 v;
        {
            int f = f0;     int bl = f / 3, c = f - 3 * bl; v.x = tile[bl * 196 + nn * 3 + c];
        }
        {
            int f = f0 + 1; int bl = f / 3, c = f - 3 * bl; v.y = tile[bl * 196 + nn * 3 + c];
        }
        {
            int f = f0 + 2; int bl = f / 3, c = f - 3 * bl; v.z = tile[bl * 196 + nn * 3 + c];
        }
        {
            int f = f0 + 3; int bl = f / 3, c = f - 3 * bl; v.w = tile[bl * 196 + nn * 3 + c];
        }
        v.x *= cs; v.y *= cs; v.z *= cs; v.w *= cs;
        outp[o4] = v;
    }
}

// ---------------- fused gather + (3->64) matmul + relu + Wfc dot ----------------
// 4 waves/block, one node per wave; lane = batch element within slab.
__global__ __launch_bounds__(256, 6) void k_main(const float* __restrict__ xs2,
                                                 const float* __restrict__ W1,
                                                 const float* __restrict__ b1,
                                                 const float* __restrict__ Wfc,
                                                 const float* __restrict__ c_dst,
                                                 const int* __restrict__ row_ptr,
                                                 const int* __restrict__ csr_src,
                                                 float* __restrict__ partial) {
    __shared__ float4 sW14[64];
    __shared__ float sWfc[4][64];
    __shared__ float red[4][64];
    int t = threadIdx.x & 63;
    int w = threadIdx.x >> 6;
    int bq = blockIdx.x & 3;            // slab; blockIdx%8 -> XCD, XCD k caches slab k%4
    int g  = blockIdx.x >> 2;           // node group [0,1024)
    int n  = g * 4 + w;
    if (w == 0) sW14[t] = make_float4(W1[t], W1[64 + t], W1[128 + t], b1[t]);
    sWfc[w][t] = Wfc[n * 64 + t];
    __syncthreads();

    const float* slab = xs2 + (size_t)bq * (Nn * 192);
    int s0 = row_ptr[n], s1 = row_ptr[n + 1];
    int vt = t * 3;
    float a0 = 0.f, a1 = 0.f, a2 = 0.f;
    int i = s0;
    for (; i + 4 <= s1; i += 4) {
        const float* p0 = slab + csr_src[i]     * 192 + vt;
        const float* p1 = slab + csr_src[i + 1] * 192 + vt;
        const float* p2 = slab + csr_src[i + 2] * 192 + vt;
        const float* p3 = slab + csr_src[i + 3] * 192 + vt;
        float u0 = p0[0], u1 = p0[1], u2 = p0[2];
        float v0 = p1[0], v1 = p1[1], v2 = p1[2];
        float w0 = p2[0], w1 = p2[1], w2 = p2[2];
        float z0 = p3[0], z1 = p3[1], z2 = p3[2];
        a0 += (u0 + v0) + (w0 + z0);
        a1 += (u1 + v1) + (w1 + z1);
        a2 += (u2 + v2) + (w2 + z2);
    }
    for (; i < s1; i++) {
        const float* p = slab + csr_src[i] * 192 + vt;
        a0 += p[0]; a1 += p[1]; a2 += p[2];
    }
    float cd = c_dst[n];
    a0 *= cd; a1 *= cd; a2 *= cd;

    float part = 0.f;
#pragma unroll 8
    for (int f = 0; f < 64; f++) {
        float4 wv = sW14[f];
        float h = fmaf(a0, wv.x, fmaf(a1, wv.y, fmaf(a2, wv.z, wv.w)));
        part = fmaf(fmaxf(h, 0.f), sWfc[w][f], part);
    }
    red[w][t] = part;
    __syncthreads();
    if (w == 0) {
        float tot = (red[0][t] + red[1][t]) + (red[2][t] + red[3][t]);
        partial[(size_t)g * 256 + bq * 64 + t] = tot;   // coalesced 256 B
    }
}

// ---------------- reduce partials over node groups ----------------
__global__ __launch_bounds__(256) void k_reduce(const float* __restrict__ partial,
                                                float* __restrict__ out_acc,
                                                int chunk) {
    int t = threadIdx.x;
    int g0 = blockIdx.x * chunk;
    float s = 0.f;
    for (int g = 0; g < chunk; g++) s += partial[(size_t)(g0 + g) * 256 + t];
    atomicAdd(&out_acc[t], s);
}

// ---------------- epilogue: sigmoid ----------------
__global__ __launch_bounds__(256) void k_final(const float* __restrict__ out_acc,
                                               const float* __restrict__ bfc,
                                               float* __restrict__ out) {
    int t = threadIdx.x;
    float v = out_acc[t] + bfc[0];
    out[t] = 1.0f / (1.0f + expf(-v));
}

extern "C" void kernel_launch(void* const* d_in, const int* in_sizes, int n_in,
                              void* d_out, int out_size, void* d_ws, size_t ws_size,
                              hipStream_t stream) {
    const float* x   = (const float*)d_in[0];
    const float* W1  = (const float*)d_in[1];
    const float* b1  = (const float*)d_in[2];
    const float* Wfc = (const float*)d_in[3];
    const float* bfc = (const float*)d_in[4];
    const int*   src = (const int*)d_in[5];
    const int*   dst = (const int*)d_in[6];
    float* out = (float*)d_out;

    char* ws = (char*)d_ws;
    float* xs2 = (float*)ws;                       // 12,582,912 B (4 slabs x 3.15 MB)
    const size_t Z = (size_t)Kk * Bg * 4;
    int*   deg_out = (int*)(ws + Z);               // zeroed block: 50176 B
    int*   deg_in  = (int*)(ws + Z + 16384);
    int*   cursor  = (int*)(ws + Z + 32768);
    float* out_acc = (float*)(ws + Z + 49152);
    float* c_src   = (float*)(ws + Z + 50176);
    float* c_dst   = (float*)(ws + Z + 66560);
    int*   row_ptr = (int*)(ws + Z + 82944);       // 4097 ints
    int*   csr_src = (int*)(ws + Z + 99344);       // 65536 ints
    float* partial = (float*)(ws + Z + 361488);    // 1024*256 floats = 1 MB

    hipMemsetAsync(ws + Z, 0, 50176, stream);
    k_degrees<<<Ee / 256, 256, 0, stream>>>(src, dst, deg_out, deg_in);
    k_norm_scan<<<1, 256, 0, stream>>>(deg_out, deg_in, c_src, c_dst, row_ptr);
    k_fill<<<Ee / 256, 256, 0, stream>>>(src, dst, row_ptr, cursor, csr_src);
    k_transpose<<<dim3(Nn / 64, 4), 256, 0, stream>>>(x, c_src, xs2);
    k_main<<<1024 * 4, 256, 0, stream>>>(xs2, W1, b1, Wfc, c_dst, row_ptr, csr_src, partial);
    k_reduce<<<64, 256, 0, stream>>>(partial, out_acc, 16);
    k_final<<<1, 256, 0, stream>>>(out_acc, bfc, out);
}